// Round 1
// baseline (960.125 us; speedup 1.0000x reference)
//
#include <hip/hip_runtime.h>
#include <hip/hip_bf16.h>
#include <stdint.h>

typedef __hip_bfloat16 bf16;
typedef __attribute__((ext_vector_type(8))) short v8s;   // 8 bf16 in 4 VGPRs
typedef __attribute__((ext_vector_type(4))) float v4f;   // MFMA C/D frag

__device__ __forceinline__ bf16 tob(float x) { return __float2bfloat16(x); }

// async global->LDS, 16B per lane; LDS dest must be wave-uniform base + lane*16
__device__ __forceinline__ void gload16(const void* g, void* l) {
  __builtin_amdgcn_global_load_lds(
      (const __attribute__((address_space(1))) uint32_t*)g,
      (__attribute__((address_space(3))) uint32_t*)l,
      16, 0, 0);
}

// ============ k-split small GEMMs: block = 16 outputs x 16 k-slices ============
// h1 = relu(fea @ W_l1 + b_l1)   (8,1024), K=1024
__global__ void k_lin1(const float* __restrict__ fea, const float* __restrict__ W,
                       const float* __restrict__ bias, float* __restrict__ h1) {
  __shared__ float red[256];
  const int nl = threadIdx.x & 15, ks = threadIdx.x >> 4;
  const int o = blockIdx.x * 16 + nl;            // 0..8191, same b within block
  const int b = o >> 10, n = o & 1023;
  const float* fr = fea + (b << 10) + ks * 64;
  const float* wp = W + (size_t)(ks * 64) * 1024 + n;
  float acc = 0.f;
#pragma unroll 8
  for (int j = 0; j < 64; ++j)
    acc = fmaf(fr[j], wp[(size_t)j * 1024], acc);
  red[threadIdx.x] = acc;
  __syncthreads();
  if (threadIdx.x < 16) {
    float s = bias[n];
#pragma unroll
    for (int i = 0; i < 16; ++i) s += red[i * 16 + threadIdx.x];
    h1[o] = fmaxf(s, 0.f);
  }
}

// x = h1 @ W_l2 + b_l2   (8,3072), K=1024 -> xf (ws) + xout (d_out)
__global__ void k_lin2(const float* __restrict__ h1, const float* __restrict__ W,
                       const float* __restrict__ bias, float* __restrict__ xf,
                       float* __restrict__ xout) {
  __shared__ float red[256];
  const int nl = threadIdx.x & 15, ks = threadIdx.x >> 4;
  const int o = blockIdx.x * 16 + nl;            // 0..24575, same b within block
  const int b = o / 3072, n = o - b * 3072;
  const float* hr = h1 + (b << 10) + ks * 64;
  const float* wp = W + (size_t)(ks * 64) * 3072 + n;
  float acc = 0.f;
#pragma unroll 8
  for (int j = 0; j < 64; ++j)
    acc = fmaf(hr[j], wp[(size_t)j * 3072], acc);
  red[threadIdx.x] = acc;
  __syncthreads();
  if (threadIdx.x < 16) {
    float s = bias[n];
#pragma unroll
    for (int i = 0; i < 16; ++i) s += red[i * 16 + threadIdx.x];
    xf[o] = s;
    xout[o] = s;
  }
}

// gp[b,n] = fea[b] @ W_c1[5:,n] + b_c1[n]   (8,512), K=1024
__global__ void k_gp(const float* __restrict__ fea, const float* __restrict__ Wc1,
                     const float* __restrict__ bc1, float* __restrict__ gp) {
  __shared__ float red[256];
  const int nl = threadIdx.x & 15, ks = threadIdx.x >> 4;
  const int o = blockIdx.x * 16 + nl;            // 0..4095
  const int b = o >> 9, n = o & 511;
  const float* fr = fea + (b << 10) + ks * 64;
  const float* wp = Wc1 + (size_t)(5 + ks * 64) * 512 + n;
  float acc = 0.f;
#pragma unroll 8
  for (int j = 0; j < 64; ++j)
    acc = fmaf(fr[j], wp[(size_t)j * 512], acc);
  red[threadIdx.x] = acc;
  __syncthreads();
  if (threadIdx.x < 16) {
    float s = bc1[n];
#pragma unroll
    for (int i = 0; i < 16; ++i) s += red[i * 16 + threadIdx.x];
    gp[o] = s;
  }
}

// W2T[n, k-swizzled] = bf16(W_c2[k,n])  (512,512), LDS-tiled.
// The 16B k-slot within each 64B K-step block is XOR-swizzled by ((n>>1)&3) so
// that a LINEAR global_load_lds copy lands the tile bank-conflict-free for the
// swizzled ds_read_b128 in k_gemm (pre-swizzled-source pattern: LDS dest of
// global_load_lds cannot be swizzled directly).
__global__ void k_w2t(const float* __restrict__ W, bf16* __restrict__ WT) {
  __shared__ float tile[32][33];
  int bx = blockIdx.x & 15, by = blockIdx.x >> 4;
  int c = threadIdx.x & 31, r8 = threadIdx.x >> 5;
#pragma unroll
  for (int i = 0; i < 4; ++i) {
    int r = r8 + i * 8;
    tile[r][c] = W[(by * 32 + r) * 512 + bx * 32 + c];
  }
  __syncthreads();
#pragma unroll
  for (int i = 0; i < 4; ++i) {
    int r = r8 + i * 8;
    int n = bx * 32 + r;                       // output row (conv2 in-channel)
    int k = by * 32 + c;                       // original k
    int s = (c >> 3) & 3;                      // 16B slot within the 64B block
    int ks = (k & ~24) | (((s ^ ((n >> 1) & 3)) & 3) << 3);  // swizzled slot
    WT[(size_t)n * 512 + ks] = tob(tile[c][r]);
  }
}

// ============ fused conv1+conv2 GEMM + conv3 epilogue ============
// 2048 blocks x 512 threads. Block: rows m0..m0+127, N-half nblk*256..+255,
// K=512, BK=32. LDS = 50688 B -> 3 blocks/CU (24 waves/CU) so barrier drains of
// one block overlap compute of the other two (m114 implicit overlap).
// A-tile computed on the fly (rank-6 conv1 factorization), B staged via gload16
// from the pre-swizzled W2T; A write/read swizzle the 16B k-slot by (row>>1)&3.
// conv3 partials (N split in 2) go to global fine via atomicAdd; fine is
// memset to 0 and nblk==0 adds bias+center.
__global__ __launch_bounds__(512, 6)
void k_gemm(const bf16* __restrict__ W2T, const float* __restrict__ Wc1,
            const float* __restrict__ gp, const float* __restrict__ xf,
            const float* __restrict__ bc2, const float* __restrict__ Wc3,
            const float* __restrict__ bc3, float* __restrict__ fine) {
  __shared__ __align__(16) bf16 As[2][128 * 32];   // 2 x 8 KB
  __shared__ __align__(16) bf16 Bs[2][256 * 32];   // 2 x 16 KB
  __shared__ float facc[128][3];                   // 1.5 KB
  const int t = threadIdx.x;
  const int mblk = blockIdx.x >> 1, nblk = blockIdx.x & 1;
  const int m0 = mblk * 128;
  const int w = t >> 6, l = t & 63, q = l >> 4, lm = l & 15;
  const int wm = (w >> 2) * 64;          // wave output-row base (0 or 64)
  const int wn = (w & 3) * 64;           // wave output-col base within N-half
  const int qs = (q ^ ((lm >> 1) & 3)) << 4;  // swizzled 16B slot for frag reads

  if (t < 384) ((float*)facc)[t] = 0.f;

  // ---- A-compute role: thread -> (row arow, k-subgroup cg of 8) ----
  const int arow = t >> 2, cg = t & 3;
  const int m = m0 + arow;
  const int b = m >> 14;                 // batch, uniform per block
  const int f = m & 16383;
  const int c = f >> 4, g = f & 15;
  const float gx = -0.05f + (float)(g & 3) * (0.1f / 3.0f);
  const float gy = -0.05f + (float)(g >> 2) * (0.1f / 3.0f);
  const float* xp = xf + (b * 1024 + c) * 3;
  const float x0 = xp[0], x1 = xp[1], x2 = xp[2];
  const float* gpr = gp + (b << 9);
  char* awr = (char*)As + arow * 64 + ((cg ^ ((arow >> 1) & 3)) << 4); // + buf*8192

  // ---- B staging role: wave stages rows [w*32, w*32+32), 2 gload16/thread ----
  const char* bsrc = (const char*)W2T +
      (size_t)(nblk * 256 + w * 32 + (l >> 2)) * 1024 + (l & 3) * 16;
  char* bdst = (char*)Bs + w * 2048 + l * 16;      // + buf*16384 + i*1024

  v4f acc[4][4];
#pragma unroll
  for (int mi = 0; mi < 4; ++mi)
#pragma unroll
    for (int ni = 0; ni < 4; ++ni) acc[mi][ni] = (v4f){0.f, 0.f, 0.f, 0.f};

  auto stage = [&](int kt, int buf) {
    // B first: get the async loads in flight
    const char* src = bsrc + kt * 64;
    char* dst = bdst + buf * 16384;
    gload16(src, dst);
    gload16(src + 16384, dst + 1024);    // +16 rows
    // A: compute 8 elems (1 row x 8 k), two half-passes to limit live temps
    const int kk = kt * 32 + cg * 8;
    union { bf16 h[8]; uint4 u; } o;
#pragma unroll
    for (int h = 0; h < 2; ++h) {
      const int kb = kk + h * 4;
      float4 gv = *(const float4*)(gpr + kb);
      float4 a0 = *(const float4*)(Wc1 + 0 * 512 + kb);
      float4 a1 = *(const float4*)(Wc1 + 1 * 512 + kb);
      float4 a2 = *(const float4*)(Wc1 + 2 * 512 + kb);
      float4 a3 = *(const float4*)(Wc1 + 3 * 512 + kb);
      float4 a4 = *(const float4*)(Wc1 + 4 * 512 + kb);
#pragma unroll
      for (int j = 0; j < 4; ++j) {
        float v = ((const float*)&gv)[j];
        v = fmaf(gx, ((const float*)&a0)[j], v);
        v = fmaf(gy, ((const float*)&a1)[j], v);
        v = fmaf(x0, ((const float*)&a2)[j], v);
        v = fmaf(x1, ((const float*)&a3)[j], v);
        v = fmaf(x2, ((const float*)&a4)[j], v);
        o.h[h * 4 + j] = tob(fmaxf(v, 0.f));
      }
    }
    *(uint4*)(awr + buf * 8192) = o.u;
  };

  stage(0, 0);

#pragma unroll 2
  for (int kt = 0; kt < 16; ++kt) {
    const int buf = kt & 1;
    __syncthreads();                     // stage(kt,buf) complete on all waves
    if (kt < 15) stage(kt + 1, buf ^ 1); // prefetch next tile (other buffer)
    const char* ab = (const char*)As + buf * 8192;
    const char* bb = (const char*)Bs + buf * 16384;
    v8s af[4], bfr[4];
#pragma unroll
    for (int mi = 0; mi < 4; ++mi)
      af[mi] = *(const v8s*)(ab + (wm + mi * 16 + lm) * 64 + qs);
#pragma unroll
    for (int ni = 0; ni < 4; ++ni)
      bfr[ni] = *(const v8s*)(bb + (wn + ni * 16 + lm) * 64 + qs);
#pragma unroll
    for (int mi = 0; mi < 4; ++mi)
#pragma unroll
      for (int ni = 0; ni < 4; ++ni)
        acc[mi][ni] = __builtin_amdgcn_mfma_f32_16x16x32_bf16(af[mi], bfr[ni], acc[mi][ni], 0, 0, 0);
  }

  // ---- epilogue: h2 = relu(acc + b_c2); fine partials via Wc3 ----
  float part[4][4][3];
#pragma unroll
  for (int mi = 0; mi < 4; ++mi)
#pragma unroll
    for (int r = 0; r < 4; ++r) { part[mi][r][0] = 0.f; part[mi][r][1] = 0.f; part[mi][r][2] = 0.f; }
#pragma unroll
  for (int ni = 0; ni < 4; ++ni) {
    const int n = nblk * 256 + wn + ni * 16 + lm;
    const float bv = bc2[n];
    const float w30 = Wc3[n * 3 + 0];
    const float w31 = Wc3[n * 3 + 1];
    const float w32 = Wc3[n * 3 + 2];
#pragma unroll
    for (int mi = 0; mi < 4; ++mi)
#pragma unroll
      for (int r = 0; r < 4; ++r) {
        float v = fmaxf(acc[mi][ni][r] + bv, 0.f);
        part[mi][r][0] = fmaf(v, w30, part[mi][r][0]);
        part[mi][r][1] = fmaf(v, w31, part[mi][r][1]);
        part[mi][r][2] = fmaf(v, w32, part[mi][r][2]);
      }
  }
#pragma unroll
  for (int mi = 0; mi < 4; ++mi)
#pragma unroll
    for (int r = 0; r < 4; ++r)
#pragma unroll
      for (int j = 0; j < 3; ++j) {
        float v = part[mi][r][j];
        v += __shfl_xor(v, 1);
        v += __shfl_xor(v, 2);
        v += __shfl_xor(v, 4);
        v += __shfl_xor(v, 8);
        if (lm == 0) atomicAdd(&facc[wm + mi * 16 + q * 4 + r][j], v);
      }
  __syncthreads();
  if (t < 128) {
    const int mm = m0 + t;
    float* fp = fine + (size_t)mm * 3;
    float base[3] = {0.f, 0.f, 0.f};
    if (nblk == 0) {
      const int bb2 = mm >> 14, cc = (mm & 16383) >> 4;
      const float* xq = xf + (bb2 * 1024 + cc) * 3;
#pragma unroll
      for (int j = 0; j < 3; ++j) base[j] = bc3[j] + xq[j];
    }
#pragma unroll
    for (int j = 0; j < 3; ++j)
      atomicAdd(&fp[j], facc[t][j] + base[j]);
  }
}

extern "C" void kernel_launch(void* const* d_in, const int* in_sizes, int n_in,
                              void* d_out, int out_size, void* d_ws, size_t ws_size,
                              hipStream_t stream) {
  const float* fea = (const float*)d_in[0];
  const float* Wl1 = (const float*)d_in[1];
  const float* bl1 = (const float*)d_in[2];
  const float* Wl2 = (const float*)d_in[3];
  const float* bl2 = (const float*)d_in[4];
  const float* Wc1 = (const float*)d_in[5];
  const float* bc1 = (const float*)d_in[6];
  const float* Wc2 = (const float*)d_in[7];
  const float* bc2 = (const float*)d_in[8];
  const float* Wc3 = (const float*)d_in[9];
  const float* bc3 = (const float*)d_in[10];
  float* xout = (float*)d_out;                // (8,1024,3)
  float* fine = (float*)d_out + 24576;        // (8,16384,3)
  char* ws = (char*)d_ws;
  float* h1  = (float*)ws;                    // 32 KB
  float* xf  = (float*)(ws + 32768);          // 96 KB
  float* gp  = (float*)(ws + 131072);         // 16 KB
  bf16*  W2T = (bf16*)(ws + 147456);          // 512 KB

  hipMemsetAsync(fine, 0, (size_t)131072 * 3 * sizeof(float), stream);
  k_lin1<<<512, 256, 0, stream>>>(fea, Wl1, bl1, h1);
  k_gp<<<256, 256, 0, stream>>>(fea, Wc1, bc1, gp);
  k_w2t<<<256, 256, 0, stream>>>(Wc2, W2T);
  k_lin2<<<1536, 256, 0, stream>>>(h1, Wl2, bl2, xf, xout);
  k_gemm<<<2048, 512, 0, stream>>>(W2T, Wc1, gp, xf, bc2, Wc3, bc3, fine);
}

// Round 2
// 264.007 us; speedup vs baseline: 3.6367x; 3.6367x over previous
//
#include <hip/hip_runtime.h>
#include <hip/hip_bf16.h>
#include <stdint.h>

typedef __hip_bfloat16 bf16;
typedef __attribute__((ext_vector_type(8))) short v8s;   // 8 bf16 in 4 VGPRs
typedef __attribute__((ext_vector_type(4))) float v4f;   // MFMA C/D frag

__device__ __forceinline__ bf16 tob(float x) { return __float2bfloat16(x); }

// async global->LDS, 16B per lane; LDS dest must be wave-uniform base + lane*16
__device__ __forceinline__ void gload16(const void* g, void* l) {
  __builtin_amdgcn_global_load_lds(
      (const __attribute__((address_space(1))) uint32_t*)g,
      (__attribute__((address_space(3))) uint32_t*)l,
      16, 0, 0);
}

// ============ k-split small GEMMs: block = 16 outputs x 16 k-slices ============
// h1 = relu(fea @ W_l1 + b_l1)   (8,1024), K=1024
__global__ void k_lin1(const float* __restrict__ fea, const float* __restrict__ W,
                       const float* __restrict__ bias, float* __restrict__ h1) {
  __shared__ float red[256];
  const int nl = threadIdx.x & 15, ks = threadIdx.x >> 4;
  const int o = blockIdx.x * 16 + nl;            // 0..8191, same b within block
  const int b = o >> 10, n = o & 1023;
  const float* fr = fea + (b << 10) + ks * 64;
  const float* wp = W + (size_t)(ks * 64) * 1024 + n;
  float acc = 0.f;
#pragma unroll 8
  for (int j = 0; j < 64; ++j)
    acc = fmaf(fr[j], wp[(size_t)j * 1024], acc);
  red[threadIdx.x] = acc;
  __syncthreads();
  if (threadIdx.x < 16) {
    float s = bias[n];
#pragma unroll
    for (int i = 0; i < 16; ++i) s += red[i * 16 + threadIdx.x];
    h1[o] = fmaxf(s, 0.f);
  }
}

// x = h1 @ W_l2 + b_l2   (8,3072), K=1024 -> xf (ws) + xout (d_out)
__global__ void k_lin2(const float* __restrict__ h1, const float* __restrict__ W,
                       const float* __restrict__ bias, float* __restrict__ xf,
                       float* __restrict__ xout) {
  __shared__ float red[256];
  const int nl = threadIdx.x & 15, ks = threadIdx.x >> 4;
  const int o = blockIdx.x * 16 + nl;            // 0..24575, same b within block
  const int b = o / 3072, n = o - b * 3072;
  const float* hr = h1 + (b << 10) + ks * 64;
  const float* wp = W + (size_t)(ks * 64) * 3072 + n;
  float acc = 0.f;
#pragma unroll 8
  for (int j = 0; j < 64; ++j)
    acc = fmaf(hr[j], wp[(size_t)j * 3072], acc);
  red[threadIdx.x] = acc;
  __syncthreads();
  if (threadIdx.x < 16) {
    float s = bias[n];
#pragma unroll
    for (int i = 0; i < 16; ++i) s += red[i * 16 + threadIdx.x];
    xf[o] = s;
    xout[o] = s;
  }
}

// gp[b,n] = fea[b] @ W_c1[5:,n] + b_c1[n]   (8,512), K=1024
__global__ void k_gp(const float* __restrict__ fea, const float* __restrict__ Wc1,
                     const float* __restrict__ bc1, float* __restrict__ gp) {
  __shared__ float red[256];
  const int nl = threadIdx.x & 15, ks = threadIdx.x >> 4;
  const int o = blockIdx.x * 16 + nl;            // 0..4095
  const int b = o >> 9, n = o & 511;
  const float* fr = fea + (b << 10) + ks * 64;
  const float* wp = Wc1 + (size_t)(5 + ks * 64) * 512 + n;
  float acc = 0.f;
#pragma unroll 8
  for (int j = 0; j < 64; ++j)
    acc = fmaf(fr[j], wp[(size_t)j * 512], acc);
  red[threadIdx.x] = acc;
  __syncthreads();
  if (threadIdx.x < 16) {
    float s = bc1[n];
#pragma unroll
    for (int i = 0; i < 16; ++i) s += red[i * 16 + threadIdx.x];
    gp[o] = s;
  }
}

// W2T[n, k-swizzled] = bf16(W_c2[k,n])  (512,512), LDS-tiled.
// The 16B k-slot within each 64B K-step block is XOR-swizzled by ((n>>1)&3) so
// that a LINEAR global_load_lds copy lands the tile bank-conflict-free for the
// swizzled ds_read_b128 in k_gemm (pre-swizzled-source pattern: LDS dest of
// global_load_lds cannot be swizzled directly).
__global__ void k_w2t(const float* __restrict__ W, bf16* __restrict__ WT) {
  __shared__ float tile[32][33];
  int bx = blockIdx.x & 15, by = blockIdx.x >> 4;
  int c = threadIdx.x & 31, r8 = threadIdx.x >> 5;
#pragma unroll
  for (int i = 0; i < 4; ++i) {
    int r = r8 + i * 8;
    tile[r][c] = W[(by * 32 + r) * 512 + bx * 32 + c];
  }
  __syncthreads();
#pragma unroll
  for (int i = 0; i < 4; ++i) {
    int r = r8 + i * 8;
    int n = bx * 32 + r;                       // output row (conv2 in-channel)
    int k = by * 32 + c;                       // original k
    int s = (c >> 3) & 3;                      // 16B slot within the 64B block
    int ks = (k & ~24) | (((s ^ ((n >> 1) & 3)) & 3) << 3);  // swizzled slot
    WT[(size_t)n * 512 + ks] = tob(tile[c][r]);
  }
}

// ============ fused conv1+conv2 GEMM + conv3 epilogue ============
// 2048 blocks x 512 threads. Block: rows m0..m0+127, N-half nblk*256..+255,
// K=512, BK=32. LDS = 50688 B and VGPR<=128 -> 2 blocks/CU (16 waves/CU), so
// one block's barrier drain overlaps the sibling's MFMAs (m114 overlap).
// NOTE: launch_bounds(512,6) (3 blocks/CU) caps VGPR at ~85 < the ~104 this
// kernel needs -> accumulator spills to scratch -> 4.3 GB HBM spill traffic,
// 872 us (round-1 regression). (512,4) caps at 128: spill-free.
// A-tile computed on the fly (rank-6 conv1 factorization), B staged via gload16
// from the pre-swizzled W2T; A write/read swizzle the 16B k-slot by (row>>1)&3.
// conv3 partials (N split in 2) go to global fine via atomicAdd; fine is
// memset to 0 and nblk==0 adds bias+center.
__global__ __launch_bounds__(512, 4)
void k_gemm(const bf16* __restrict__ W2T, const float* __restrict__ Wc1,
            const float* __restrict__ gp, const float* __restrict__ xf,
            const float* __restrict__ bc2, const float* __restrict__ Wc3,
            const float* __restrict__ bc3, float* __restrict__ fine) {
  __shared__ __align__(16) bf16 As[2][128 * 32];   // 2 x 8 KB
  __shared__ __align__(16) bf16 Bs[2][256 * 32];   // 2 x 16 KB
  __shared__ float facc[128][3];                   // 1.5 KB
  const int t = threadIdx.x;
  const int mblk = blockIdx.x >> 1, nblk = blockIdx.x & 1;
  const int m0 = mblk * 128;
  const int w = t >> 6, l = t & 63, q = l >> 4, lm = l & 15;
  const int wm = (w >> 2) * 64;          // wave output-row base (0 or 64)
  const int wn = (w & 3) * 64;           // wave output-col base within N-half
  const int qs = (q ^ ((lm >> 1) & 3)) << 4;  // swizzled 16B slot for frag reads

  if (t < 384) ((float*)facc)[t] = 0.f;

  // ---- A-compute role: thread -> (row arow, k-subgroup cg of 8) ----
  const int arow = t >> 2, cg = t & 3;
  const int m = m0 + arow;
  const int b = m >> 14;                 // batch, uniform per block
  const int f = m & 16383;
  const int c = f >> 4, g = f & 15;
  const float gx = -0.05f + (float)(g & 3) * (0.1f / 3.0f);
  const float gy = -0.05f + (float)(g >> 2) * (0.1f / 3.0f);
  const float* xp = xf + (b * 1024 + c) * 3;
  const float x0 = xp[0], x1 = xp[1], x2 = xp[2];
  const float* gpr = gp + (b << 9);
  char* awr = (char*)As + arow * 64 + ((cg ^ ((arow >> 1) & 3)) << 4); // + buf*8192

  // ---- B staging role: wave stages rows [w*32, w*32+32), 2 gload16/thread ----
  const char* bsrc = (const char*)W2T +
      (size_t)(nblk * 256 + w * 32 + (l >> 2)) * 1024 + (l & 3) * 16;
  char* bdst = (char*)Bs + w * 2048 + l * 16;      // + buf*16384 + i*1024

  v4f acc[4][4];
#pragma unroll
  for (int mi = 0; mi < 4; ++mi)
#pragma unroll
    for (int ni = 0; ni < 4; ++ni) acc[mi][ni] = (v4f){0.f, 0.f, 0.f, 0.f};

  auto stage = [&](int kt, int buf) {
    // B first: get the async loads in flight
    const char* src = bsrc + kt * 64;
    char* dst = bdst + buf * 16384;
    gload16(src, dst);
    gload16(src + 16384, dst + 1024);    // +16 rows
    // A: compute 8 elems (1 row x 8 k), two half-passes to limit live temps
    const int kk = kt * 32 + cg * 8;
    union { bf16 h[8]; uint4 u; } o;
#pragma unroll
    for (int h = 0; h < 2; ++h) {
      const int kb = kk + h * 4;
      float4 gv = *(const float4*)(gpr + kb);
      float4 a0 = *(const float4*)(Wc1 + 0 * 512 + kb);
      float4 a1 = *(const float4*)(Wc1 + 1 * 512 + kb);
      float4 a2 = *(const float4*)(Wc1 + 2 * 512 + kb);
      float4 a3 = *(const float4*)(Wc1 + 3 * 512 + kb);
      float4 a4 = *(const float4*)(Wc1 + 4 * 512 + kb);
#pragma unroll
      for (int j = 0; j < 4; ++j) {
        float v = ((const float*)&gv)[j];
        v = fmaf(gx, ((const float*)&a0)[j], v);
        v = fmaf(gy, ((const float*)&a1)[j], v);
        v = fmaf(x0, ((const float*)&a2)[j], v);
        v = fmaf(x1, ((const float*)&a3)[j], v);
        v = fmaf(x2, ((const float*)&a4)[j], v);
        o.h[h * 4 + j] = tob(fmaxf(v, 0.f));
      }
    }
    *(uint4*)(awr + buf * 8192) = o.u;
  };

  stage(0, 0);

#pragma unroll 2
  for (int kt = 0; kt < 16; ++kt) {
    const int buf = kt & 1;
    __syncthreads();                     // stage(kt,buf) complete on all waves
    if (kt < 15) stage(kt + 1, buf ^ 1); // prefetch next tile (other buffer)
    const char* ab = (const char*)As + buf * 8192;
    const char* bb = (const char*)Bs + buf * 16384;
    v8s af[4], bfr[4];
#pragma unroll
    for (int mi = 0; mi < 4; ++mi)
      af[mi] = *(const v8s*)(ab + (wm + mi * 16 + lm) * 64 + qs);
#pragma unroll
    for (int ni = 0; ni < 4; ++ni)
      bfr[ni] = *(const v8s*)(bb + (wn + ni * 16 + lm) * 64 + qs);
#pragma unroll
    for (int mi = 0; mi < 4; ++mi)
#pragma unroll
      for (int ni = 0; ni < 4; ++ni)
        acc[mi][ni] = __builtin_amdgcn_mfma_f32_16x16x32_bf16(af[mi], bfr[ni], acc[mi][ni], 0, 0, 0);
  }

  // ---- epilogue: h2 = relu(acc + b_c2); fine partials via Wc3 ----
  float part[4][4][3];
#pragma unroll
  for (int mi = 0; mi < 4; ++mi)
#pragma unroll
    for (int r = 0; r < 4; ++r) { part[mi][r][0] = 0.f; part[mi][r][1] = 0.f; part[mi][r][2] = 0.f; }
#pragma unroll
  for (int ni = 0; ni < 4; ++ni) {
    const int n = nblk * 256 + wn + ni * 16 + lm;
    const float bv = bc2[n];
    const float w30 = Wc3[n * 3 + 0];
    const float w31 = Wc3[n * 3 + 1];
    const float w32 = Wc3[n * 3 + 2];
#pragma unroll
    for (int mi = 0; mi < 4; ++mi)
#pragma unroll
      for (int r = 0; r < 4; ++r) {
        float v = fmaxf(acc[mi][ni][r] + bv, 0.f);
        part[mi][r][0] = fmaf(v, w30, part[mi][r][0]);
        part[mi][r][1] = fmaf(v, w31, part[mi][r][1]);
        part[mi][r][2] = fmaf(v, w32, part[mi][r][2]);
      }
  }
#pragma unroll
  for (int mi = 0; mi < 4; ++mi)
#pragma unroll
    for (int r = 0; r < 4; ++r)
#pragma unroll
      for (int j = 0; j < 3; ++j) {
        float v = part[mi][r][j];
        v += __shfl_xor(v, 1);
        v += __shfl_xor(v, 2);
        v += __shfl_xor(v, 4);
        v += __shfl_xor(v, 8);
        if (lm == 0) atomicAdd(&facc[wm + mi * 16 + q * 4 + r][j], v);
      }
  __syncthreads();
  if (t < 128) {
    const int mm = m0 + t;
    float* fp = fine + (size_t)mm * 3;
    float base[3] = {0.f, 0.f, 0.f};
    if (nblk == 0) {
      const int bb2 = mm >> 14, cc = (mm & 16383) >> 4;
      const float* xq = xf + (bb2 * 1024 + cc) * 3;
#pragma unroll
      for (int j = 0; j < 3; ++j) base[j] = bc3[j] + xq[j];
    }
#pragma unroll
    for (int j = 0; j < 3; ++j)
      atomicAdd(&fp[j], facc[t][j] + base[j]);
  }
}

extern "C" void kernel_launch(void* const* d_in, const int* in_sizes, int n_in,
                              void* d_out, int out_size, void* d_ws, size_t ws_size,
                              hipStream_t stream) {
  const float* fea = (const float*)d_in[0];
  const float* Wl1 = (const float*)d_in[1];
  const float* bl1 = (const float*)d_in[2];
  const float* Wl2 = (const float*)d_in[3];
  const float* bl2 = (const float*)d_in[4];
  const float* Wc1 = (const float*)d_in[5];
  const float* bc1 = (const float*)d_in[6];
  const float* Wc2 = (const float*)d_in[7];
  const float* bc2 = (const float*)d_in[8];
  const float* Wc3 = (const float*)d_in[9];
  const float* bc3 = (const float*)d_in[10];
  float* xout = (float*)d_out;                // (8,1024,3)
  float* fine = (float*)d_out + 24576;        // (8,16384,3)
  char* ws = (char*)d_ws;
  float* h1  = (float*)ws;                    // 32 KB
  float* xf  = (float*)(ws + 32768);          // 96 KB
  float* gp  = (float*)(ws + 131072);         // 16 KB
  bf16*  W2T = (bf16*)(ws + 147456);          // 512 KB

  hipMemsetAsync(fine, 0, (size_t)131072 * 3 * sizeof(float), stream);
  k_lin1<<<512, 256, 0, stream>>>(fea, Wl1, bl1, h1);
  k_gp<<<256, 256, 0, stream>>>(fea, Wc1, bc1, gp);
  k_w2t<<<256, 256, 0, stream>>>(Wc2, W2T);
  k_lin2<<<1536, 256, 0, stream>>>(h1, Wl2, bl2, xf, xout);
  k_gemm<<<2048, 512, 0, stream>>>(W2T, Wc1, gp, xf, bc2, Wc3, bc3, fine);
}

// Round 3
// 227.325 us; speedup vs baseline: 4.2236x; 1.1614x over previous
//
#include <hip/hip_runtime.h>
#include <hip/hip_bf16.h>
#include <stdint.h>

typedef __hip_bfloat16 bf16;
typedef __attribute__((ext_vector_type(8))) short v8s;   // 8 bf16 in 4 VGPRs
typedef __attribute__((ext_vector_type(4))) float v4f;   // MFMA C/D frag

__device__ __forceinline__ bf16 tob(float x) { return __float2bfloat16(x); }

// async global->LDS, 16B per lane; LDS dest must be wave-uniform base + lane*16
__device__ __forceinline__ void gload16(const void* g, void* l) {
  __builtin_amdgcn_global_load_lds(
      (const __attribute__((address_space(1))) uint32_t*)g,
      (__attribute__((address_space(3))) uint32_t*)l,
      16, 0, 0);
}

// ============ k-split small GEMMs: block = 16 outputs x 16 k-slices ============
// h1 = relu(fea @ W_l1 + b_l1)   (8,1024), K=1024
__global__ void k_lin1(const float* __restrict__ fea, const float* __restrict__ W,
                       const float* __restrict__ bias, float* __restrict__ h1) {
  __shared__ float red[256];
  const int nl = threadIdx.x & 15, ks = threadIdx.x >> 4;
  const int o = blockIdx.x * 16 + nl;            // 0..8191, same b within block
  const int b = o >> 10, n = o & 1023;
  const float* fr = fea + (b << 10) + ks * 64;
  const float* wp = W + (size_t)(ks * 64) * 1024 + n;
  float acc = 0.f;
#pragma unroll 8
  for (int j = 0; j < 64; ++j)
    acc = fmaf(fr[j], wp[(size_t)j * 1024], acc);
  red[threadIdx.x] = acc;
  __syncthreads();
  if (threadIdx.x < 16) {
    float s = bias[n];
#pragma unroll
    for (int i = 0; i < 16; ++i) s += red[i * 16 + threadIdx.x];
    h1[o] = fmaxf(s, 0.f);
  }
}

// x = h1 @ W_l2 + b_l2   (8,3072), K=1024 -> xf (ws) + xout (d_out)
__global__ void k_lin2(const float* __restrict__ h1, const float* __restrict__ W,
                       const float* __restrict__ bias, float* __restrict__ xf,
                       float* __restrict__ xout) {
  __shared__ float red[256];
  const int nl = threadIdx.x & 15, ks = threadIdx.x >> 4;
  const int o = blockIdx.x * 16 + nl;            // 0..24575, same b within block
  const int b = o / 3072, n = o - b * 3072;
  const float* hr = h1 + (b << 10) + ks * 64;
  const float* wp = W + (size_t)(ks * 64) * 3072 + n;
  float acc = 0.f;
#pragma unroll 8
  for (int j = 0; j < 64; ++j)
    acc = fmaf(hr[j], wp[(size_t)j * 3072], acc);
  red[threadIdx.x] = acc;
  __syncthreads();
  if (threadIdx.x < 16) {
    float s = bias[n];
#pragma unroll
    for (int i = 0; i < 16; ++i) s += red[i * 16 + threadIdx.x];
    xf[o] = s;
    xout[o] = s;
  }
}

// gp[b,n] = fea[b] @ W_c1[5:,n] + b_c1[n]   (8,512), K=1024
__global__ void k_gp(const float* __restrict__ fea, const float* __restrict__ Wc1,
                     const float* __restrict__ bc1, float* __restrict__ gp) {
  __shared__ float red[256];
  const int nl = threadIdx.x & 15, ks = threadIdx.x >> 4;
  const int o = blockIdx.x * 16 + nl;            // 0..4095
  const int b = o >> 9, n = o & 511;
  const float* fr = fea + (b << 10) + ks * 64;
  const float* wp = Wc1 + (size_t)(5 + ks * 64) * 512 + n;
  float acc = 0.f;
#pragma unroll 8
  for (int j = 0; j < 64; ++j)
    acc = fmaf(fr[j], wp[(size_t)j * 512], acc);
  red[threadIdx.x] = acc;
  __syncthreads();
  if (threadIdx.x < 16) {
    float s = bc1[n];
#pragma unroll
    for (int i = 0; i < 16; ++i) s += red[i * 16 + threadIdx.x];
    gp[o] = s;
  }
}

// G[g,k] = gx(g)*Wc1[0,k] + gy(g)*Wc1[1,k]   (16,512) f32, 32 KB
__global__ void k_grid(const float* __restrict__ Wc1, float* __restrict__ G) {
  const int k = threadIdx.x;          // 512 threads
  const int g = blockIdx.x;           // 16 blocks
  const float gx = -0.05f + (float)(g & 3) * (0.1f / 3.0f);
  const float gy = -0.05f + (float)(g >> 2) * (0.1f / 3.0f);
  G[g * 512 + k] = fmaf(gy, Wc1[512 + k], gx * Wc1[k]);
}

// P[b*1024+c, k] = gp[b,k] + x0*Wc1[2,k] + x1*Wc1[3,k] + x2*Wc1[4,k]
// (8192,512) f32, 16 MB. Hoists the per-coarse-point part of the conv1 input
// out of k_gemm's inner loop (it was recomputed 16 kt x 2 nblk times per row).
__global__ void k_pp(const float* __restrict__ gp, const float* __restrict__ xf,
                     const float* __restrict__ Wc1, float* __restrict__ P) {
  const int t = threadIdx.x;                    // 512
  const int row = blockIdx.x * 4 + (t >> 7);    // (b,c), 2048 blocks
  const int k4 = (t & 127) << 2;
  const int b = row >> 10;
  const float* xp = xf + row * 3;
  const float x0 = xp[0], x1 = xp[1], x2 = xp[2];
  float4 gv = *(const float4*)(gp + (b << 9) + k4);
  float4 w2 = *(const float4*)(Wc1 + 2 * 512 + k4);
  float4 w3 = *(const float4*)(Wc1 + 3 * 512 + k4);
  float4 w4 = *(const float4*)(Wc1 + 4 * 512 + k4);
  float4 r;
  r.x = fmaf(x2, w4.x, fmaf(x1, w3.x, fmaf(x0, w2.x, gv.x)));
  r.y = fmaf(x2, w4.y, fmaf(x1, w3.y, fmaf(x0, w2.y, gv.y)));
  r.z = fmaf(x2, w4.z, fmaf(x1, w3.z, fmaf(x0, w2.z, gv.z)));
  r.w = fmaf(x2, w4.w, fmaf(x1, w3.w, fmaf(x0, w2.w, gv.w)));
  *(float4*)(P + (size_t)row * 512 + k4) = r;
}

// W2T[n, k-swizzled] = bf16(W_c2[k,n])  (512,512), LDS-tiled.
// The 16B k-slot within each 64B K-step block is XOR-swizzled by ((n>>1)&3) so
// that a LINEAR global_load_lds copy lands the tile bank-conflict-free for the
// swizzled ds_read_b128 in k_gemm (pre-swizzled-source pattern: LDS dest of
// global_load_lds cannot be swizzled directly).
__global__ void k_w2t(const float* __restrict__ W, bf16* __restrict__ WT) {
  __shared__ float tile[32][33];
  int bx = blockIdx.x & 15, by = blockIdx.x >> 4;
  int c = threadIdx.x & 31, r8 = threadIdx.x >> 5;
#pragma unroll
  for (int i = 0; i < 4; ++i) {
    int r = r8 + i * 8;
    tile[r][c] = W[(by * 32 + r) * 512 + bx * 32 + c];
  }
  __syncthreads();
#pragma unroll
  for (int i = 0; i < 4; ++i) {
    int r = r8 + i * 8;
    int n = bx * 32 + r;                       // output row (conv2 in-channel)
    int k = by * 32 + c;                       // original k
    int s = (c >> 3) & 3;                      // 16B slot within the 64B block
    int ks = (k & ~24) | (((s ^ ((n >> 1) & 3)) & 3) << 3);  // swizzled slot
    WT[(size_t)n * 512 + ks] = tob(tile[c][r]);
  }
}

// ============ fused conv1+conv2 GEMM + conv3 epilogue ============
// 2048 blocks x 512 threads. Block: rows m0..m0+127, N-half nblk*256..+255,
// K=512, BK=32. LDS = 50688 B and VGPR<=128 -> 2 blocks/CU (16 waves/CU), so
// one block's barrier drain overlaps the sibling's MFMAs (m114 overlap).
// launch_bounds(512,6) spills the 64-reg accumulator (round-1: 4.3 GB scratch
// traffic, 872 us) -- keep (512,4).
// A-tile per kt: A[row,k] = relu(P[b,c,k] + G[g,k]) -- 4 float4 loads + 8 add/
// max/cvt per thread (round-2's rank-6 recompute was 12 loads + ~50 VALU).
// B staged via gload16 from pre-swizzled W2T; A write/read swizzle the 16B
// k-slot by (row>>1)&3. conv3 partials (N split in 2) -> global atomicAdd.
__global__ __launch_bounds__(512, 4)
void k_gemm(const bf16* __restrict__ W2T, const float* __restrict__ P,
            const float* __restrict__ G, const float* __restrict__ xf,
            const float* __restrict__ bc2, const float* __restrict__ Wc3,
            const float* __restrict__ bc3, float* __restrict__ fine) {
  __shared__ __align__(16) bf16 As[2][128 * 32];   // 2 x 8 KB
  __shared__ __align__(16) bf16 Bs[2][256 * 32];   // 2 x 16 KB
  __shared__ float facc[128][3];                   // 1.5 KB
  const int t = threadIdx.x;
  const int mblk = blockIdx.x >> 1, nblk = blockIdx.x & 1;
  const int m0 = mblk * 128;
  const int w = t >> 6, l = t & 63, q = l >> 4, lm = l & 15;
  const int wm = (w >> 2) * 64;          // wave output-row base (0 or 64)
  const int wn = (w & 3) * 64;           // wave output-col base within N-half
  const int qs = (q ^ ((lm >> 1) & 3)) << 4;  // swizzled 16B slot for frag reads

  if (t < 384) ((float*)facc)[t] = 0.f;

  // ---- A-compute role: thread -> (row arow, k-subgroup cg of 8) ----
  const int arow = t >> 2, cg = t & 3;
  const int m = m0 + arow;
  const int b = m >> 14;                 // batch, uniform per block
  const int f = m & 16383;
  const int c = f >> 4, g = f & 15;
  const float* pr = P + ((size_t)(b * 1024 + c) << 9);  // P row (512 f32)
  const float* gr = G + (g << 9);                       // G row (512 f32)
  char* awr = (char*)As + arow * 64 + ((cg ^ ((arow >> 1) & 3)) << 4); // + buf*8192

  // ---- B staging role: wave stages rows [w*32, w*32+32), 2 gload16/thread ----
  const char* bsrc = (const char*)W2T +
      (size_t)(nblk * 256 + w * 32 + (l >> 2)) * 1024 + (l & 3) * 16;
  char* bdst = (char*)Bs + w * 2048 + l * 16;      // + buf*16384 + i*1024

  v4f acc[4][4];
#pragma unroll
  for (int mi = 0; mi < 4; ++mi)
#pragma unroll
    for (int ni = 0; ni < 4; ++ni) acc[mi][ni] = (v4f){0.f, 0.f, 0.f, 0.f};

  auto stage = [&](int kt, int buf) {
    // B first: get the async loads in flight
    const char* src = bsrc + kt * 64;
    char* dst = bdst + buf * 16384;
    gload16(src, dst);
    gload16(src + 16384, dst + 1024);    // +16 rows
    // A: relu(P + G), 8 elems (1 row x 8 k); 4 independent float4 loads
    const int kk = kt * 32 + cg * 8;
    union { bf16 h[8]; uint4 u; } o;
    float4 p0 = *(const float4*)(pr + kk);
    float4 p1 = *(const float4*)(pr + kk + 4);
    float4 g0 = *(const float4*)(gr + kk);
    float4 g1 = *(const float4*)(gr + kk + 4);
#pragma unroll
    for (int j = 0; j < 4; ++j) {
      o.h[j]     = tob(fmaxf(((const float*)&p0)[j] + ((const float*)&g0)[j], 0.f));
      o.h[4 + j] = tob(fmaxf(((const float*)&p1)[j] + ((const float*)&g1)[j], 0.f));
    }
    *(uint4*)(awr + buf * 8192) = o.u;
  };

  stage(0, 0);

#pragma unroll 2
  for (int kt = 0; kt < 16; ++kt) {
    const int buf = kt & 1;
    __syncthreads();                     // stage(kt,buf) complete on all waves
    if (kt < 15) stage(kt + 1, buf ^ 1); // prefetch next tile (other buffer)
    const char* ab = (const char*)As + buf * 8192;
    const char* bb = (const char*)Bs + buf * 16384;
    v8s af[4], bfr[4];
#pragma unroll
    for (int mi = 0; mi < 4; ++mi)
      af[mi] = *(const v8s*)(ab + (wm + mi * 16 + lm) * 64 + qs);
#pragma unroll
    for (int ni = 0; ni < 4; ++ni)
      bfr[ni] = *(const v8s*)(bb + (wn + ni * 16 + lm) * 64 + qs);
#pragma unroll
    for (int mi = 0; mi < 4; ++mi)
#pragma unroll
      for (int ni = 0; ni < 4; ++ni)
        acc[mi][ni] = __builtin_amdgcn_mfma_f32_16x16x32_bf16(af[mi], bfr[ni], acc[mi][ni], 0, 0, 0);
  }

  // ---- epilogue: h2 = relu(acc + b_c2); fine partials via Wc3 ----
  float part[4][4][3];
#pragma unroll
  for (int mi = 0; mi < 4; ++mi)
#pragma unroll
    for (int r = 0; r < 4; ++r) { part[mi][r][0] = 0.f; part[mi][r][1] = 0.f; part[mi][r][2] = 0.f; }
#pragma unroll
  for (int ni = 0; ni < 4; ++ni) {
    const int n = nblk * 256 + wn + ni * 16 + lm;
    const float bv = bc2[n];
    const float w30 = Wc3[n * 3 + 0];
    const float w31 = Wc3[n * 3 + 1];
    const float w32 = Wc3[n * 3 + 2];
#pragma unroll
    for (int mi = 0; mi < 4; ++mi)
#pragma unroll
      for (int r = 0; r < 4; ++r) {
        float v = fmaxf(acc[mi][ni][r] + bv, 0.f);
        part[mi][r][0] = fmaf(v, w30, part[mi][r][0]);
        part[mi][r][1] = fmaf(v, w31, part[mi][r][1]);
        part[mi][r][2] = fmaf(v, w32, part[mi][r][2]);
      }
  }
#pragma unroll
  for (int mi = 0; mi < 4; ++mi)
#pragma unroll
    for (int r = 0; r < 4; ++r)
#pragma unroll
      for (int j = 0; j < 3; ++j) {
        float v = part[mi][r][j];
        v += __shfl_xor(v, 1);
        v += __shfl_xor(v, 2);
        v += __shfl_xor(v, 4);
        v += __shfl_xor(v, 8);
        if (lm == 0) atomicAdd(&facc[wm + mi * 16 + q * 4 + r][j], v);
      }
  __syncthreads();
  if (t < 128) {
    const int mm = m0 + t;
    float* fp = fine + (size_t)mm * 3;
    float base[3] = {0.f, 0.f, 0.f};
    if (nblk == 0) {
      const int bb2 = mm >> 14, cc = (mm & 16383) >> 4;
      const float* xq = xf + (bb2 * 1024 + cc) * 3;
#pragma unroll
      for (int j = 0; j < 3; ++j) base[j] = bc3[j] + xq[j];
    }
#pragma unroll
    for (int j = 0; j < 3; ++j)
      atomicAdd(&fp[j], facc[t][j] + base[j]);
  }
}

extern "C" void kernel_launch(void* const* d_in, const int* in_sizes, int n_in,
                              void* d_out, int out_size, void* d_ws, size_t ws_size,
                              hipStream_t stream) {
  const float* fea = (const float*)d_in[0];
  const float* Wl1 = (const float*)d_in[1];
  const float* bl1 = (const float*)d_in[2];
  const float* Wl2 = (const float*)d_in[3];
  const float* bl2 = (const float*)d_in[4];
  const float* Wc1 = (const float*)d_in[5];
  const float* bc1 = (const float*)d_in[6];
  const float* Wc2 = (const float*)d_in[7];
  const float* bc2 = (const float*)d_in[8];
  const float* Wc3 = (const float*)d_in[9];
  const float* bc3 = (const float*)d_in[10];
  float* xout = (float*)d_out;                // (8,1024,3)
  float* fine = (float*)d_out + 24576;        // (8,16384,3)
  char* ws = (char*)d_ws;
  float* h1  = (float*)ws;                    // 32 KB
  float* xf  = (float*)(ws + 32768);          // 96 KB
  float* gp  = (float*)(ws + 131072);         // 16 KB
  bf16*  W2T = (bf16*)(ws + 147456);          // 512 KB
  float* G   = (float*)(ws + 671744);         // 32 KB
  float* P   = (float*)(ws + 704512);         // 16 MB

  hipMemsetAsync(fine, 0, (size_t)131072 * 3 * sizeof(float), stream);
  k_grid<<<16, 512, 0, stream>>>(Wc1, G);
  k_lin1<<<512, 256, 0, stream>>>(fea, Wl1, bl1, h1);
  k_gp<<<256, 256, 0, stream>>>(fea, Wc1, bc1, gp);
  k_w2t<<<256, 256, 0, stream>>>(Wc2, W2T);
  k_lin2<<<1536, 256, 0, stream>>>(h1, Wl2, bl2, xf, xout);
  k_pp<<<2048, 512, 0, stream>>>(gp, xf, Wc1, P);
  k_gemm<<<2048, 512, 0, stream>>>(W2T, P, G, xf, bc2, Wc3, bc3, fine);
}